// Round 24
// baseline (44.330 us; speedup 1.0000x reference)
//
#include <hip/hip_runtime.h>
#include <hip/hip_bf16.h>

#define NWN    100000
#define NTN    1600
#define NDOC   16384
#define EWD    1000000
#define ETD    200000
#define NWORD  15000
#define NTOPIC 50
#define HD     128
#define NB     32
#define NSW    64       // word-hist slabs (u8-packed)
#define NSD    64       // doc-hist slabs (u16-packed pairs)
#define NST    32       // topic-hist slabs
#define NSU    64       // u-role blocks
#define WRDW   25000    // u32 words holding 100000 u8 counters
#define NBLK_E 256      // edge blocks: one per CU
#define BDIM_E 640      // 10 waves/block
#define STRIDE_E (NBLK_E * BDIM_E)   // 163840 threads
#define NU4    300000   // total int4 units
#define NWAVE_E (BDIM_E / 64)        // 10

// ---- ws layout (u32 words) ----
#define O_SLABW 0         // NSW*WRDW = 1600000
#define O_SLABD 1600000   // NSD*NDOC = 1048576
#define O_SLABT 2648576   // NST*NTN  = 51200
#define O_DOCS  2699776   // 16384 packed (wd lo16 | td hi16)
#define O_UNW   2716160   // 100000 f32
#define O_UNT   2816160   // 1600 f32
#define O_UW    2816768   // 15000 f32 (v no longer stored globally)
#define O_UT    2831768   // 64 f32
#define O_ACC   2831832   // 32 f32
#define O_CNT   2831864   // 8 u32

// --- 1) histograms + embedding-dot (u) + init, one kernel, 225 blocks -------
__global__ void __launch_bounds__(1024) a_histuv(const int* __restrict__ wd_src,
                                                 const int* __restrict__ wd_dst,
                                                 const int* __restrict__ td_src,
                                                 const int* __restrict__ td_dst,
                                                 const float* __restrict__ wemb,
                                                 const float* __restrict__ temb,
                                                 const float* __restrict__ Wwd,
                                                 const float* __restrict__ Wtd,
                                                 const float* __restrict__ Wout,
                                                 unsigned* __restrict__ ws) {
    __shared__ unsigned h[WRDW];          // 100 KB (word role); reused by others
    int tid = threadIdx.x;
    int b   = blockIdx.x;
    if (b < NSW) {
        for (int k = tid; k < WRDW; k += 1024) h[k] = 0u;
        __syncthreads();
        const int4* p = (const int4*)wd_src;
        for (int i = b * 1024 + tid; i < EWD / 4; i += NSW * 1024) {
            int4 s = p[i];
            atomicAdd(&h[((unsigned)s.x) >> 2], 1u << (8 * (s.x & 3)));
            atomicAdd(&h[((unsigned)s.y) >> 2], 1u << (8 * (s.y & 3)));
            atomicAdd(&h[((unsigned)s.z) >> 2], 1u << (8 * (s.z & 3)));
            atomicAdd(&h[((unsigned)s.w) >> 2], 1u << (8 * (s.w & 3)));
        }
        __syncthreads();
        unsigned* slab = ws + O_SLABW + b * WRDW;
        for (int k = tid; k < WRDW; k += 1024) slab[k] = h[k];
    } else if (b < NSW + NSD) {
        int sb = b - NSW;
        for (int k = tid; k < NDOC; k += 1024) h[k] = 0u;
        __syncthreads();
        const int4* p = (const int4*)wd_dst;
        for (int i = sb * 1024 + tid; i < EWD / 4; i += NSD * 1024) {
            int4 d = p[i];
            atomicAdd(&h[d.x], 1u); atomicAdd(&h[d.y], 1u);
            atomicAdd(&h[d.z], 1u); atomicAdd(&h[d.w], 1u);
        }
        const int4* q = (const int4*)td_dst;
        for (int i = sb * 1024 + tid; i < ETD / 4; i += NSD * 1024) {
            int4 d = q[i];
            atomicAdd(&h[d.x], 65536u); atomicAdd(&h[d.y], 65536u);
            atomicAdd(&h[d.z], 65536u); atomicAdd(&h[d.w], 65536u);
        }
        __syncthreads();
        unsigned* slab = ws + O_SLABD + sb * NDOC;
        for (int k = tid; k < NDOC; k += 1024) slab[k] = h[k];
    } else if (b < NSW + NSD + NST) {
        int sb = b - NSW - NSD;
        for (int k = tid; k < NTN; k += 1024) h[k] = 0u;
        __syncthreads();
        const int4* p = (const int4*)td_src;
        for (int i = sb * 1024 + tid; i < ETD / 4; i += NST * 1024) {
            int4 s = p[i];
            atomicAdd(&h[s.x], 1u); atomicAdd(&h[s.y], 1u);
            atomicAdd(&h[s.z], 1u); atomicAdd(&h[s.w], 1u);
        }
        __syncthreads();
        unsigned* slab = ws + O_SLABT + sb * NTN;
        for (int k = tid; k < NTN; k += 1024) slab[k] = h[k];
    } else if (b < NSW + NSD + NST + NSU) {
        // u-role: compute v locally, then wave-per-row embedding dots
        int ub = b - NSW - NSD - NST;
        float* hw = (float*)h;            // [0..127]=wout, [128..255]=v_wd, [256..383]=v_td
        if (tid < HD) hw[tid] = Wout[tid];
        __syncthreads();
        if (tid < HD) {
            float s1 = 0.f;
            for (int j = 0; j < HD; ++j) s1 += Wwd[tid * HD + j] * hw[j];
            hw[HD + tid] = s1;
        } else if (tid < 2 * HD) {
            int t2 = tid - HD;
            float s2 = 0.f;
            for (int j = 0; j < HD; ++j) s2 += Wtd[t2 * HD + j] * hw[j];
            hw[2 * HD + t2] = s2;
        }
        __syncthreads();
        int wave = tid >> 6;
        int lane = tid & 63;
        float* u_wd = (float*)(ws + O_UW);
        float* u_td = (float*)(ws + O_UT);
        for (int row = ub * 16 + wave; row < NWORD + NTOPIC; row += NSU * 16) {
            const float* src; const float* vv; float* dst; int r;
            if (row < NWORD) { src = wemb; vv = hw + HD;     dst = u_wd; r = row; }
            else             { src = temb; vv = hw + 2 * HD; dst = u_td; r = row - NWORD; }
            float s = src[r * HD + lane]      * vv[lane]
                    + src[r * HD + lane + 64] * vv[lane + 64];
            #pragma unroll
            for (int off = 32; off; off >>= 1) s += __shfl_down(s, off);
            if (lane == 0) dst[r] = s;
        }
    } else {
        // init role: zero acc + done-counter
        if (tid < NB) ((float*)(ws + O_ACC))[tid] = 0.f;
        if (tid == NB) ws[O_CNT] = 0u;
    }
}

// --- 2) reduce slabs + fold outdeg norm + embedding gather ------------------
__global__ void f_un(const int* __restrict__ wids, const int* __restrict__ tids,
                     unsigned* __restrict__ ws) {
    const unsigned* slabW = ws + O_SLABW;
    const unsigned* slabD = ws + O_SLABD;
    const unsigned* slabT = ws + O_SLABT;
    unsigned* docs = ws + O_DOCS;
    const float* u_wd = (const float*)(ws + O_UW);
    const float* u_td = (const float*)(ws + O_UT);
    float* un_w = (float*)(ws + O_UNW);
    float* un_t = (float*)(ws + O_UNT);
    int t = blockIdx.x * blockDim.x + threadIdx.x;
    if (t < NWN) {
        int w = t >> 2, sh = 8 * (t & 3);
        unsigned d = 0u;
        #pragma unroll
        for (int j = 0; j < NSW; ++j) d += (slabW[j * WRDW + w] >> sh) & 0xFFu;
        un_w[t] = u_wd[wids[t]] * rsqrtf((float)(d > 1u ? d : 1u));
    } else if (t < NWN + NDOC) {
        int k = t - NWN;
        unsigned s = 0u;
        #pragma unroll
        for (int j = 0; j < NSD; ++j) s += slabD[j * NDOC + k];
        docs[k] = s;
    } else if (t < NWN + NDOC + NTN) {
        int k = t - NWN - NDOC;
        unsigned d = 0u;
        #pragma unroll
        for (int j = 0; j < NST; ++j) d += slabT[j * NTN + k];
        un_t[k] = u_td[tids[k]] * rsqrtf((float)(d > 1u ? d : 1u));
    }
}

// --- 3) edges: docs in LDS, 2 units/thread, 10 waves/CU, + last-block fin ---
__global__ void __launch_bounds__(BDIM_E) d_edges_fin(const int* __restrict__ wd_src,
                                                      const int* __restrict__ wd_dst,
                                                      const int* __restrict__ td_src,
                                                      const int* __restrict__ td_dst,
                                                      const float* __restrict__ y_data,
                                                      const float* __restrict__ b_wd,
                                                      const float* __restrict__ b_td,
                                                      const float* __restrict__ Wout,
                                                      const float* __restrict__ b_out,
                                                      unsigned* __restrict__ ws,
                                                      float* __restrict__ out) {
    const float* un_w = (const float*)(ws + O_UNW);
    const float* un_t = (const float*)(ws + O_UNT);
    float* acc = (float*)(ws + O_ACC);
    __shared__ unsigned sdocs[NDOC];              // 64 KB
    __shared__ float lacc[NWAVE_E][NB];
    __shared__ unsigned lastflag;
    int tid = threadIdx.x;
    int wv  = tid >> 6;

    // phase 1: issue stream loads (long latency, independent of LDS fill)
    int4 sv[2], dv[2];
    int kind[2];
    int gid = blockIdx.x * BDIM_E + tid;
    #pragma unroll
    for (int k = 0; k < 2; ++k) {
        int u = gid + k * STRIDE_E;
        if (u < EWD / 4) {
            sv[k] = ((const int4*)wd_src)[u];
            dv[k] = ((const int4*)wd_dst)[u];
            kind[k] = 0;
        } else if (u < NU4) {
            int e = u - EWD / 4;
            sv[k] = ((const int4*)td_src)[e];
            dv[k] = ((const int4*)td_dst)[e];
            kind[k] = 1;
        } else {
            kind[k] = 2;
        }
    }
    // fill docs into LDS (coalesced uint4) + zero lacc
    {
        const uint4* dsrc = (const uint4*)(ws + O_DOCS);
        uint4* ddst = (uint4*)sdocs;
        for (int k = tid; k < NDOC / 4; k += BDIM_E) ddst[k] = dsrc[k];
        if (tid < NWAVE_E * NB) ((float*)lacc)[tid] = 0.f;
    }
    __syncthreads();
    float* wacc = lacc[wv];

    // phase 2: gathers (un_* from L1/L2, docs from LDS) + LDS accumulate
    #pragma unroll
    for (int k = 0; k < 2; ++k) {
        int4 s = sv[k], d = dv[k];
        unsigned b;
        if (kind[k] == 0) {
            b = sdocs[d.x] & 0xFFFFu;
            atomicAdd(&wacc[d.x >> 9], un_w[s.x] * rsqrtf((float)(b > 1u ? b : 1u)));
            b = sdocs[d.y] & 0xFFFFu;
            atomicAdd(&wacc[d.y >> 9], un_w[s.y] * rsqrtf((float)(b > 1u ? b : 1u)));
            b = sdocs[d.z] & 0xFFFFu;
            atomicAdd(&wacc[d.z >> 9], un_w[s.z] * rsqrtf((float)(b > 1u ? b : 1u)));
            b = sdocs[d.w] & 0xFFFFu;
            atomicAdd(&wacc[d.w >> 9], un_w[s.w] * rsqrtf((float)(b > 1u ? b : 1u)));
        } else if (kind[k] == 1) {
            b = sdocs[d.x] >> 16;
            atomicAdd(&wacc[d.x >> 9], un_t[s.x] * rsqrtf((float)(b > 1u ? b : 1u)));
            b = sdocs[d.y] >> 16;
            atomicAdd(&wacc[d.y >> 9], un_t[s.y] * rsqrtf((float)(b > 1u ? b : 1u)));
            b = sdocs[d.z] >> 16;
            atomicAdd(&wacc[d.z >> 9], un_t[s.z] * rsqrtf((float)(b > 1u ? b : 1u)));
            b = sdocs[d.w] >> 16;
            atomicAdd(&wacc[d.w >> 9], un_t[s.w] * rsqrtf((float)(b > 1u ? b : 1u)));
        }
    }
    __syncthreads();
    if (tid < NB) {
        float s = 0.f;
        #pragma unroll
        for (int j = 0; j < NWAVE_E; ++j) s += lacc[j][tid];
        atomicAdd(&acc[tid], s);
    }
    if (tid == 0) {
        __threadfence();
        unsigned prev = atomicAdd(&ws[O_CNT], 1u);
        lastflag = (prev == (unsigned)gridDim.x - 1u) ? 1u : 0u;
    }
    __syncthreads();
    if (lastflag && tid < 64) {
        float p = (b_wd[tid] + b_td[tid]) * Wout[tid]
                + (b_wd[tid + 64] + b_td[tid + 64]) * Wout[tid + 64];
        #pragma unroll
        for (int off = 32; off; off >>= 1) p += __shfl_down(p, off);
        float c0 = __shfl(p, 0) + b_out[0];
        float l = 0.f;
        if (tid < NB) {
            float a = atomicAdd(&acc[tid], 0.0f);   // coherent read
            float x = a * (1.0f / 512.0f) + c0;
            float y = y_data[tid];
            l = fmaxf(x, 0.f) - x * y + log1pf(expf(-fabsf(x)));
            out[1 + tid] = 1.0f / (1.0f + expf(-x));
        }
        #pragma unroll
        for (int off = 16; off; off >>= 1) l += __shfl_down(l, off);
        if (tid == 0) out[0] = l * (1.0f / (float)NB);
    }
}

extern "C" void kernel_launch(void* const* d_in, const int* in_sizes, int n_in,
                              void* d_out, int out_size, void* d_ws, size_t ws_size,
                              hipStream_t stream) {
    const int* word_ids  = (const int*)d_in[0];
    const int* topic_ids = (const int*)d_in[1];
    const int* wd_src    = (const int*)d_in[2];
    const int* wd_dst    = (const int*)d_in[3];
    const int* td_src    = (const int*)d_in[4];
    const int* td_dst    = (const int*)d_in[5];
    const float* y_data  = (const float*)d_in[6];
    const float* wemb    = (const float*)d_in[7];
    const float* temb    = (const float*)d_in[8];
    const float* Wwd     = (const float*)d_in[9];
    const float* bwd     = (const float*)d_in[10];
    const float* Wtd     = (const float*)d_in[11];
    const float* btd     = (const float*)d_in[12];
    const float* Wout    = (const float*)d_in[13];
    const float* bout    = (const float*)d_in[14];
    float* out = (float*)d_out;
    unsigned* ws = (unsigned*)d_ws;

    a_histuv<<<NSW + NSD + NST + NSU + 1, 1024, 0, stream>>>(
        wd_src, wd_dst, td_src, td_dst, wemb, temb, Wwd, Wtd, Wout, ws);
    f_un<<<(NWN + NDOC + NTN + 255) / 256, 256, 0, stream>>>(word_ids, topic_ids, ws);
    d_edges_fin<<<NBLK_E, BDIM_E, 0, stream>>>(wd_src, wd_dst, td_src, td_dst,
                                               y_data, bwd, btd, Wout, bout, ws, out);
}

// Round 25
// 41.612 us; speedup vs baseline: 1.0653x; 1.0653x over previous
//
#include <hip/hip_runtime.h>
#include <hip/hip_bf16.h>

#define NWN    100000
#define NTN    1600
#define NDOC   16384
#define EWD    1000000
#define ETD    200000
#define NWORD  15000
#define NTOPIC 50
#define HD     128
#define NB     32
#define NSW    64       // word-hist slabs (u8-packed)
#define NSD    64       // doc-hist slabs (u16-packed pairs)
#define NST    32       // topic-hist slabs
#define WRDW   25000    // u32 words holding 100000 u8 counters
#define NBLK_E 256      // edge blocks: one per CU
#define BDIM_E 640      // 10 waves/block
#define STRIDE_E (NBLK_E * BDIM_E)   // 163840 threads
#define NU4    300000   // total int4 units: EWD/4 + ETD/4
#define NWAVE_E (BDIM_E / 64)        // 10

// ---- ws layout (u32 words) ----
#define O_SLABW 0         // NSW*WRDW = 1600000
#define O_SLABD 1600000   // NSD*NDOC = 1048576
#define O_SLABT 2648576   // NST*NTN  = 51200
#define O_DOCS  2699776   // 16384 packed (wd lo16 | td hi16)
#define O_UNW   2716160   // 100000 f32
#define O_UNT   2816160   // 1600 f32
#define O_V     2817760   // 256 f32
#define O_UW    2818016   // 15000 f32
#define O_UT    2833016   // 64 f32
#define O_ACC   2833080   // 32 f32
#define O_CNT   2833112   // 8 u32

// --- 1) histograms (blocks 0..159) + v/acc/cnt init (block 160) -------------
__global__ void __launch_bounds__(1024) a_histv(const int* __restrict__ wd_src,
                                                const int* __restrict__ wd_dst,
                                                const int* __restrict__ td_src,
                                                const int* __restrict__ td_dst,
                                                const float* __restrict__ Wwd,
                                                const float* __restrict__ Wtd,
                                                const float* __restrict__ Wout,
                                                unsigned* __restrict__ ws) {
    __shared__ unsigned h[WRDW];          // 100 KB max (word role)
    int tid = threadIdx.x;
    int b   = blockIdx.x;
    if (b < NSW) {
        for (int k = tid; k < WRDW; k += 1024) h[k] = 0u;
        __syncthreads();
        const int4* p = (const int4*)wd_src;
        for (int i = b * 1024 + tid; i < EWD / 4; i += NSW * 1024) {
            int4 s = p[i];
            atomicAdd(&h[((unsigned)s.x) >> 2], 1u << (8 * (s.x & 3)));
            atomicAdd(&h[((unsigned)s.y) >> 2], 1u << (8 * (s.y & 3)));
            atomicAdd(&h[((unsigned)s.z) >> 2], 1u << (8 * (s.z & 3)));
            atomicAdd(&h[((unsigned)s.w) >> 2], 1u << (8 * (s.w & 3)));
        }
        __syncthreads();
        unsigned* slab = ws + O_SLABW + b * WRDW;
        for (int k = tid; k < WRDW; k += 1024) slab[k] = h[k];
    } else if (b < NSW + NSD) {
        int sb = b - NSW;
        for (int k = tid; k < NDOC; k += 1024) h[k] = 0u;
        __syncthreads();
        const int4* p = (const int4*)wd_dst;
        for (int i = sb * 1024 + tid; i < EWD / 4; i += NSD * 1024) {
            int4 d = p[i];
            atomicAdd(&h[d.x], 1u); atomicAdd(&h[d.y], 1u);
            atomicAdd(&h[d.z], 1u); atomicAdd(&h[d.w], 1u);
        }
        const int4* q = (const int4*)td_dst;
        for (int i = sb * 1024 + tid; i < ETD / 4; i += NSD * 1024) {
            int4 d = q[i];
            atomicAdd(&h[d.x], 65536u); atomicAdd(&h[d.y], 65536u);
            atomicAdd(&h[d.z], 65536u); atomicAdd(&h[d.w], 65536u);
        }
        __syncthreads();
        unsigned* slab = ws + O_SLABD + sb * NDOC;
        for (int k = tid; k < NDOC; k += 1024) slab[k] = h[k];
    } else if (b < NSW + NSD + NST) {
        int sb = b - NSW - NSD;
        for (int k = tid; k < NTN; k += 1024) h[k] = 0u;
        __syncthreads();
        const int4* p = (const int4*)td_src;
        for (int i = sb * 1024 + tid; i < ETD / 4; i += NST * 1024) {
            int4 s = p[i];
            atomicAdd(&h[s.x], 1u); atomicAdd(&h[s.y], 1u);
            atomicAdd(&h[s.z], 1u); atomicAdd(&h[s.w], 1u);
        }
        __syncthreads();
        unsigned* slab = ws + O_SLABT + sb * NTN;
        for (int k = tid; k < NTN; k += 1024) slab[k] = h[k];
    } else {
        // v = [W_wd @ W_out | W_td @ W_out]; zero acc + done-counter
        if (tid < HD) {
            float* hw = (float*)h;
            hw[tid] = Wout[tid];
            __syncthreads();
            float s1 = 0.f, s2 = 0.f;
            for (int j = 0; j < HD; ++j) {
                s1 += Wwd[tid * HD + j] * hw[j];
                s2 += Wtd[tid * HD + j] * hw[j];
            }
            float* v = (float*)(ws + O_V);
            v[tid]      = s1;
            v[tid + HD] = s2;
            if (tid < NB) ((float*)(ws + O_ACC))[tid] = 0.f;
            if (tid == NB) ws[O_CNT] = 0u;
        } else {
            __syncthreads();   // match the t<HD barrier
        }
    }
}

// --- 2) u[row] = emb_row . v  (one wave per row) -----------------------------
__global__ void f_u(const float* __restrict__ wemb, const float* __restrict__ temb,
                    unsigned* __restrict__ ws) {
    const float* v = (const float*)(ws + O_V);
    int wave = threadIdx.x >> 6;
    int lane = threadIdx.x & 63;
    int row  = blockIdx.x * (blockDim.x >> 6) + wave;
    const float* src; const float* vv; float* dst; int r;
    if (row < NWORD) {
        src = wemb; vv = v; dst = (float*)(ws + O_UW); r = row;
    } else if (row < NWORD + NTOPIC) {
        src = temb; vv = v + HD; dst = (float*)(ws + O_UT); r = row - NWORD;
    } else return;
    float s = src[r * HD + lane]      * vv[lane]
            + src[r * HD + lane + 64] * vv[lane + 64];
    #pragma unroll
    for (int off = 32; off; off >>= 1) s += __shfl_down(s, off);
    if (lane == 0) dst[r] = s;
}

// --- 3) reduce slabs + fold outdeg norm + embedding gather ------------------
__global__ void f_un(const int* __restrict__ wids, const int* __restrict__ tids,
                     unsigned* __restrict__ ws) {
    const unsigned* slabW = ws + O_SLABW;
    const unsigned* slabD = ws + O_SLABD;
    const unsigned* slabT = ws + O_SLABT;
    unsigned* docs = ws + O_DOCS;
    const float* u_wd = (const float*)(ws + O_UW);
    const float* u_td = (const float*)(ws + O_UT);
    float* un_w = (float*)(ws + O_UNW);
    float* un_t = (float*)(ws + O_UNT);
    int t = blockIdx.x * blockDim.x + threadIdx.x;
    if (t < NWN) {
        int w = t >> 2, sh = 8 * (t & 3);
        unsigned d = 0u;
        #pragma unroll
        for (int j = 0; j < NSW; ++j) d += (slabW[j * WRDW + w] >> sh) & 0xFFu;
        un_w[t] = u_wd[wids[t]] * rsqrtf((float)(d > 1u ? d : 1u));
    } else if (t < NWN + NDOC) {
        int k = t - NWN;
        unsigned s = 0u;
        #pragma unroll
        for (int j = 0; j < NSD; ++j) s += slabD[j * NDOC + k];
        docs[k] = s;
    } else if (t < NWN + NDOC + NTN) {
        int k = t - NWN - NDOC;
        unsigned d = 0u;
        #pragma unroll
        for (int j = 0; j < NST; ++j) d += slabT[j * NTN + k];
        un_t[k] = u_td[tids[k]] * rsqrtf((float)(d > 1u ? d : 1u));
    }
}

// --- 4) edges: 256 blocks x 640 thr (10 waves/CU), 2 units/thread, + fin ----
__global__ void __launch_bounds__(BDIM_E) d_edges_fin(const int* __restrict__ wd_src,
                                                      const int* __restrict__ wd_dst,
                                                      const int* __restrict__ td_src,
                                                      const int* __restrict__ td_dst,
                                                      const float* __restrict__ y_data,
                                                      const float* __restrict__ b_wd,
                                                      const float* __restrict__ b_td,
                                                      const float* __restrict__ Wout,
                                                      const float* __restrict__ b_out,
                                                      unsigned* __restrict__ ws,
                                                      float* __restrict__ out) {
    const unsigned* docs = ws + O_DOCS;
    const float* un_w = (const float*)(ws + O_UNW);
    const float* un_t = (const float*)(ws + O_UNT);
    float* acc = (float*)(ws + O_ACC);
    __shared__ float lacc[NWAVE_E][NB];
    __shared__ unsigned lastflag;
    int tid = threadIdx.x;
    int wv  = tid >> 6;
    if (tid < NWAVE_E * NB) ((float*)lacc)[tid] = 0.f;
    __syncthreads();
    float* wacc = lacc[wv];

    // phase 1: stage both units' stream loads (independent)
    int4 sv[2], dv[2];
    int kind[2];
    int gid = blockIdx.x * BDIM_E + tid;
    #pragma unroll
    for (int k = 0; k < 2; ++k) {
        int u = gid + k * STRIDE_E;
        if (u < EWD / 4) {
            sv[k] = ((const int4*)wd_src)[u];
            dv[k] = ((const int4*)wd_dst)[u];
            kind[k] = 0;
        } else if (u < NU4) {
            int e = u - EWD / 4;
            sv[k] = ((const int4*)td_src)[e];
            dv[k] = ((const int4*)td_dst)[e];
            kind[k] = 1;
        } else {
            kind[k] = 2;
        }
    }
    // phase 2: 16 independent gathers + LDS accumulate (un_* non-temporal:
    // keep the high-reuse docs[] lines resident in L1 instead)
    #pragma unroll
    for (int k = 0; k < 2; ++k) {
        int4 s = sv[k], d = dv[k];
        unsigned b;
        if (kind[k] == 0) {
            b = docs[d.x] & 0xFFFFu;
            atomicAdd(&wacc[d.x >> 9], __builtin_nontemporal_load(&un_w[s.x]) *
                      rsqrtf((float)(b > 1u ? b : 1u)));
            b = docs[d.y] & 0xFFFFu;
            atomicAdd(&wacc[d.y >> 9], __builtin_nontemporal_load(&un_w[s.y]) *
                      rsqrtf((float)(b > 1u ? b : 1u)));
            b = docs[d.z] & 0xFFFFu;
            atomicAdd(&wacc[d.z >> 9], __builtin_nontemporal_load(&un_w[s.z]) *
                      rsqrtf((float)(b > 1u ? b : 1u)));
            b = docs[d.w] & 0xFFFFu;
            atomicAdd(&wacc[d.w >> 9], __builtin_nontemporal_load(&un_w[s.w]) *
                      rsqrtf((float)(b > 1u ? b : 1u)));
        } else if (kind[k] == 1) {
            b = docs[d.x] >> 16;
            atomicAdd(&wacc[d.x >> 9], __builtin_nontemporal_load(&un_t[s.x]) *
                      rsqrtf((float)(b > 1u ? b : 1u)));
            b = docs[d.y] >> 16;
            atomicAdd(&wacc[d.y >> 9], __builtin_nontemporal_load(&un_t[s.y]) *
                      rsqrtf((float)(b > 1u ? b : 1u)));
            b = docs[d.z] >> 16;
            atomicAdd(&wacc[d.z >> 9], __builtin_nontemporal_load(&un_t[s.z]) *
                      rsqrtf((float)(b > 1u ? b : 1u)));
            b = docs[d.w] >> 16;
            atomicAdd(&wacc[d.w >> 9], __builtin_nontemporal_load(&un_t[s.w]) *
                      rsqrtf((float)(b > 1u ? b : 1u)));
        }
    }
    __syncthreads();
    if (tid < NB) {
        float s = 0.f;
        #pragma unroll
        for (int j = 0; j < NWAVE_E; ++j) s += lacc[j][tid];
        atomicAdd(&acc[tid], s);
    }
    if (tid == 0) {
        __threadfence();
        unsigned prev = atomicAdd(&ws[O_CNT], 1u);
        lastflag = (prev == (unsigned)gridDim.x - 1u) ? 1u : 0u;
    }
    __syncthreads();
    if (lastflag && tid < 64) {
        float p = (b_wd[tid] + b_td[tid]) * Wout[tid]
                + (b_wd[tid + 64] + b_td[tid + 64]) * Wout[tid + 64];
        #pragma unroll
        for (int off = 32; off; off >>= 1) p += __shfl_down(p, off);
        float c0 = __shfl(p, 0) + b_out[0];
        float l = 0.f;
        if (tid < NB) {
            float a = atomicAdd(&acc[tid], 0.0f);   // coherent read
            float x = a * (1.0f / 512.0f) + c0;
            float y = y_data[tid];
            l = fmaxf(x, 0.f) - x * y + log1pf(expf(-fabsf(x)));
            out[1 + tid] = 1.0f / (1.0f + expf(-x));
        }
        #pragma unroll
        for (int off = 16; off; off >>= 1) l += __shfl_down(l, off);
        if (tid == 0) out[0] = l * (1.0f / (float)NB);
    }
}

extern "C" void kernel_launch(void* const* d_in, const int* in_sizes, int n_in,
                              void* d_out, int out_size, void* d_ws, size_t ws_size,
                              hipStream_t stream) {
    const int* word_ids  = (const int*)d_in[0];
    const int* topic_ids = (const int*)d_in[1];
    const int* wd_src    = (const int*)d_in[2];
    const int* wd_dst    = (const int*)d_in[3];
    const int* td_src    = (const int*)d_in[4];
    const int* td_dst    = (const int*)d_in[5];
    const float* y_data  = (const float*)d_in[6];
    const float* wemb    = (const float*)d_in[7];
    const float* temb    = (const float*)d_in[8];
    const float* Wwd     = (const float*)d_in[9];
    const float* bwd     = (const float*)d_in[10];
    const float* Wtd     = (const float*)d_in[11];
    const float* btd     = (const float*)d_in[12];
    const float* Wout    = (const float*)d_in[13];
    const float* bout    = (const float*)d_in[14];
    float* out = (float*)d_out;
    unsigned* ws = (unsigned*)d_ws;

    a_histv<<<NSW + NSD + NST + 1, 1024, 0, stream>>>(
        wd_src, wd_dst, td_src, td_dst, Wwd, Wtd, Wout, ws);
    f_u<<<(NWORD + NTOPIC + 3) / 4, 256, 0, stream>>>(wemb, temb, ws);
    f_un<<<(NWN + NDOC + NTN + 255) / 256, 256, 0, stream>>>(word_ids, topic_ids, ws);
    d_edges_fin<<<NBLK_E, BDIM_E, 0, stream>>>(wd_src, wd_dst, td_src, td_dst,
                                               y_data, bwd, btd, Wout, bout, ws, out);
}

// Round 26
// 39.700 us; speedup vs baseline: 1.1166x; 1.0482x over previous
//
#include <hip/hip_runtime.h>
#include <hip/hip_bf16.h>

#define NWN    100000
#define NTN    1600
#define NDOC   16384
#define EWD    1000000
#define ETD    200000
#define NWORD  15000
#define NTOPIC 50
#define HD     128
#define NB     32
#define NSW    64       // word-hist slabs (u8-packed)
#define NSD    64       // doc-hist slabs (u16-packed pairs)
#define NST    32       // topic-hist slabs
#define WRDW   25000    // u32 words holding 100000 u8 counters
#define NBLK_E 256      // edge blocks: one per CU
#define BDIM_E 640      // 10 waves/block
#define STRIDE_E (NBLK_E * BDIM_E)   // 163840 threads
#define NU4    300000   // total int4 units: EWD/4 + ETD/4
#define NWAVE_E (BDIM_E / 64)        // 10

// ---- ws layout (u32 words) ----
#define O_SLABW 0         // NSW*WRDW = 1600000
#define O_SLABD 1600000   // NSD*NDOC = 1048576
#define O_SLABT 2648576   // NST*NTN  = 51200
#define O_DOCS  2699776   // 16384 packed (wd lo16 | td hi16)
#define O_UNW   2716160   // 100000 f32
#define O_UNT   2816160   // 1600 f32
#define O_V     2817760   // 256 f32
#define O_UW    2818016   // 15000 f32
#define O_UT    2833016   // 64 f32
#define O_ACC   2833080   // 32 f32
#define O_CNT   2833112   // 8 u32

// --- 1) histograms (blocks 0..159) + v/acc/cnt init (block 160) -------------
__global__ void __launch_bounds__(1024) a_histv(const int* __restrict__ wd_src,
                                                const int* __restrict__ wd_dst,
                                                const int* __restrict__ td_src,
                                                const int* __restrict__ td_dst,
                                                const float* __restrict__ Wwd,
                                                const float* __restrict__ Wtd,
                                                const float* __restrict__ Wout,
                                                unsigned* __restrict__ ws) {
    __shared__ unsigned h[WRDW];          // 100 KB max (word role)
    int tid = threadIdx.x;
    int b   = blockIdx.x;
    if (b < NSW) {
        for (int k = tid; k < WRDW; k += 1024) h[k] = 0u;
        __syncthreads();
        const int4* p = (const int4*)wd_src;
        for (int i = b * 1024 + tid; i < EWD / 4; i += NSW * 1024) {
            int4 s = p[i];
            atomicAdd(&h[((unsigned)s.x) >> 2], 1u << (8 * (s.x & 3)));
            atomicAdd(&h[((unsigned)s.y) >> 2], 1u << (8 * (s.y & 3)));
            atomicAdd(&h[((unsigned)s.z) >> 2], 1u << (8 * (s.z & 3)));
            atomicAdd(&h[((unsigned)s.w) >> 2], 1u << (8 * (s.w & 3)));
        }
        __syncthreads();
        unsigned* slab = ws + O_SLABW + b * WRDW;
        for (int k = tid; k < WRDW; k += 1024) slab[k] = h[k];
    } else if (b < NSW + NSD) {
        int sb = b - NSW;
        for (int k = tid; k < NDOC; k += 1024) h[k] = 0u;
        __syncthreads();
        const int4* p = (const int4*)wd_dst;
        for (int i = sb * 1024 + tid; i < EWD / 4; i += NSD * 1024) {
            int4 d = p[i];
            atomicAdd(&h[d.x], 1u); atomicAdd(&h[d.y], 1u);
            atomicAdd(&h[d.z], 1u); atomicAdd(&h[d.w], 1u);
        }
        const int4* q = (const int4*)td_dst;
        for (int i = sb * 1024 + tid; i < ETD / 4; i += NSD * 1024) {
            int4 d = q[i];
            atomicAdd(&h[d.x], 65536u); atomicAdd(&h[d.y], 65536u);
            atomicAdd(&h[d.z], 65536u); atomicAdd(&h[d.w], 65536u);
        }
        __syncthreads();
        unsigned* slab = ws + O_SLABD + sb * NDOC;
        for (int k = tid; k < NDOC; k += 1024) slab[k] = h[k];
    } else if (b < NSW + NSD + NST) {
        int sb = b - NSW - NSD;
        for (int k = tid; k < NTN; k += 1024) h[k] = 0u;
        __syncthreads();
        const int4* p = (const int4*)td_src;
        for (int i = sb * 1024 + tid; i < ETD / 4; i += NST * 1024) {
            int4 s = p[i];
            atomicAdd(&h[s.x], 1u); atomicAdd(&h[s.y], 1u);
            atomicAdd(&h[s.z], 1u); atomicAdd(&h[s.w], 1u);
        }
        __syncthreads();
        unsigned* slab = ws + O_SLABT + sb * NTN;
        for (int k = tid; k < NTN; k += 1024) slab[k] = h[k];
    } else {
        // v = [W_wd @ W_out | W_td @ W_out]; zero acc + done-counter
        if (tid < HD) {
            float* hw = (float*)h;
            hw[tid] = Wout[tid];
            __syncthreads();
            float s1 = 0.f, s2 = 0.f;
            for (int j = 0; j < HD; ++j) {
                s1 += Wwd[tid * HD + j] * hw[j];
                s2 += Wtd[tid * HD + j] * hw[j];
            }
            float* v = (float*)(ws + O_V);
            v[tid]      = s1;
            v[tid + HD] = s2;
            if (tid < NB) ((float*)(ws + O_ACC))[tid] = 0.f;
            if (tid == NB) ws[O_CNT] = 0u;
        } else {
            __syncthreads();   // match the t<HD barrier
        }
    }
}

// --- 2) u[row] = emb_row . v  (one wave per row) -----------------------------
__global__ void f_u(const float* __restrict__ wemb, const float* __restrict__ temb,
                    unsigned* __restrict__ ws) {
    const float* v = (const float*)(ws + O_V);
    int wave = threadIdx.x >> 6;
    int lane = threadIdx.x & 63;
    int row  = blockIdx.x * (blockDim.x >> 6) + wave;
    const float* src; const float* vv; float* dst; int r;
    if (row < NWORD) {
        src = wemb; vv = v; dst = (float*)(ws + O_UW); r = row;
    } else if (row < NWORD + NTOPIC) {
        src = temb; vv = v + HD; dst = (float*)(ws + O_UT); r = row - NWORD;
    } else return;
    float s = src[r * HD + lane]      * vv[lane]
            + src[r * HD + lane + 64] * vv[lane + 64];
    #pragma unroll
    for (int off = 32; off; off >>= 1) s += __shfl_down(s, off);
    if (lane == 0) dst[r] = s;
}

// --- 3) reduce slabs + fold outdeg norm + embedding gather ------------------
__global__ void f_un(const int* __restrict__ wids, const int* __restrict__ tids,
                     unsigned* __restrict__ ws) {
    const unsigned* slabW = ws + O_SLABW;
    const unsigned* slabD = ws + O_SLABD;
    const unsigned* slabT = ws + O_SLABT;
    unsigned* docs = ws + O_DOCS;
    const float* u_wd = (const float*)(ws + O_UW);
    const float* u_td = (const float*)(ws + O_UT);
    float* un_w = (float*)(ws + O_UNW);
    float* un_t = (float*)(ws + O_UNT);
    int t = blockIdx.x * blockDim.x + threadIdx.x;
    if (t < NWN) {
        int w = t >> 2, sh = 8 * (t & 3);
        unsigned d = 0u;
        #pragma unroll
        for (int j = 0; j < NSW; ++j) d += (slabW[j * WRDW + w] >> sh) & 0xFFu;
        un_w[t] = u_wd[wids[t]] * rsqrtf((float)(d > 1u ? d : 1u));
    } else if (t < NWN + NDOC) {
        int k = t - NWN;
        unsigned s = 0u;
        #pragma unroll
        for (int j = 0; j < NSD; ++j) s += slabD[j * NDOC + k];
        docs[k] = s;
    } else if (t < NWN + NDOC + NTN) {
        int k = t - NWN - NDOC;
        unsigned d = 0u;
        #pragma unroll
        for (int j = 0; j < NST; ++j) d += slabT[j * NTN + k];
        un_t[k] = u_td[tids[k]] * rsqrtf((float)(d > 1u ? d : 1u));
    }
}

// --- 4) edges: 256 blocks x 640 thr (10 waves/CU), 2 units/thread, + fin ----
__global__ void __launch_bounds__(BDIM_E) d_edges_fin(const int* __restrict__ wd_src,
                                                      const int* __restrict__ wd_dst,
                                                      const int* __restrict__ td_src,
                                                      const int* __restrict__ td_dst,
                                                      const float* __restrict__ y_data,
                                                      const float* __restrict__ b_wd,
                                                      const float* __restrict__ b_td,
                                                      const float* __restrict__ Wout,
                                                      const float* __restrict__ b_out,
                                                      unsigned* __restrict__ ws,
                                                      float* __restrict__ out) {
    const unsigned* docs = ws + O_DOCS;
    const float* un_w = (const float*)(ws + O_UNW);
    const float* un_t = (const float*)(ws + O_UNT);
    float* acc = (float*)(ws + O_ACC);
    __shared__ float lacc[NWAVE_E][NB];
    __shared__ unsigned lastflag;
    int tid = threadIdx.x;
    int wv  = tid >> 6;
    if (tid < NWAVE_E * NB) ((float*)lacc)[tid] = 0.f;
    __syncthreads();
    float* wacc = lacc[wv];

    // phase 1: stage both units' stream loads (independent)
    int4 sv[2], dv[2];
    int kind[2];
    int gid = blockIdx.x * BDIM_E + tid;
    #pragma unroll
    for (int k = 0; k < 2; ++k) {
        int u = gid + k * STRIDE_E;
        if (u < EWD / 4) {
            sv[k] = ((const int4*)wd_src)[u];
            dv[k] = ((const int4*)wd_dst)[u];
            kind[k] = 0;
        } else if (u < NU4) {
            int e = u - EWD / 4;
            sv[k] = ((const int4*)td_src)[e];
            dv[k] = ((const int4*)td_dst)[e];
            kind[k] = 1;
        } else {
            kind[k] = 2;
        }
    }
    // phase 2: 16 independent gathers + LDS accumulate
    #pragma unroll
    for (int k = 0; k < 2; ++k) {
        int4 s = sv[k], d = dv[k];
        unsigned b;
        if (kind[k] == 0) {
            b = docs[d.x] & 0xFFFFu;
            atomicAdd(&wacc[d.x >> 9], un_w[s.x] * rsqrtf((float)(b > 1u ? b : 1u)));
            b = docs[d.y] & 0xFFFFu;
            atomicAdd(&wacc[d.y >> 9], un_w[s.y] * rsqrtf((float)(b > 1u ? b : 1u)));
            b = docs[d.z] & 0xFFFFu;
            atomicAdd(&wacc[d.z >> 9], un_w[s.z] * rsqrtf((float)(b > 1u ? b : 1u)));
            b = docs[d.w] & 0xFFFFu;
            atomicAdd(&wacc[d.w >> 9], un_w[s.w] * rsqrtf((float)(b > 1u ? b : 1u)));
        } else if (kind[k] == 1) {
            b = docs[d.x] >> 16;
            atomicAdd(&wacc[d.x >> 9], un_t[s.x] * rsqrtf((float)(b > 1u ? b : 1u)));
            b = docs[d.y] >> 16;
            atomicAdd(&wacc[d.y >> 9], un_t[s.y] * rsqrtf((float)(b > 1u ? b : 1u)));
            b = docs[d.z] >> 16;
            atomicAdd(&wacc[d.z >> 9], un_t[s.z] * rsqrtf((float)(b > 1u ? b : 1u)));
            b = docs[d.w] >> 16;
            atomicAdd(&wacc[d.w >> 9], un_t[s.w] * rsqrtf((float)(b > 1u ? b : 1u)));
        }
    }
    __syncthreads();
    if (tid < NB) {
        float s = 0.f;
        #pragma unroll
        for (int j = 0; j < NWAVE_E; ++j) s += lacc[j][tid];
        atomicAdd(&acc[tid], s);
    }
    if (tid == 0) {
        __threadfence();
        unsigned prev = atomicAdd(&ws[O_CNT], 1u);
        lastflag = (prev == (unsigned)gridDim.x - 1u) ? 1u : 0u;
    }
    __syncthreads();
    if (lastflag && tid < 64) {
        float p = (b_wd[tid] + b_td[tid]) * Wout[tid]
                + (b_wd[tid + 64] + b_td[tid + 64]) * Wout[tid + 64];
        #pragma unroll
        for (int off = 32; off; off >>= 1) p += __shfl_down(p, off);
        float c0 = __shfl(p, 0) + b_out[0];
        float l = 0.f;
        if (tid < NB) {
            float a = atomicAdd(&acc[tid], 0.0f);   // coherent read
            float x = a * (1.0f / 512.0f) + c0;
            float y = y_data[tid];
            l = fmaxf(x, 0.f) - x * y + log1pf(expf(-fabsf(x)));
            out[1 + tid] = 1.0f / (1.0f + expf(-x));
        }
        #pragma unroll
        for (int off = 16; off; off >>= 1) l += __shfl_down(l, off);
        if (tid == 0) out[0] = l * (1.0f / (float)NB);
    }
}

extern "C" void kernel_launch(void* const* d_in, const int* in_sizes, int n_in,
                              void* d_out, int out_size, void* d_ws, size_t ws_size,
                              hipStream_t stream) {
    const int* word_ids  = (const int*)d_in[0];
    const int* topic_ids = (const int*)d_in[1];
    const int* wd_src    = (const int*)d_in[2];
    const int* wd_dst    = (const int*)d_in[3];
    const int* td_src    = (const int*)d_in[4];
    const int* td_dst    = (const int*)d_in[5];
    const float* y_data  = (const float*)d_in[6];
    const float* wemb    = (const float*)d_in[7];
    const float* temb    = (const float*)d_in[8];
    const float* Wwd     = (const float*)d_in[9];
    const float* bwd     = (const float*)d_in[10];
    const float* Wtd     = (const float*)d_in[11];
    const float* btd     = (const float*)d_in[12];
    const float* Wout    = (const float*)d_in[13];
    const float* bout    = (const float*)d_in[14];
    float* out = (float*)d_out;
    unsigned* ws = (unsigned*)d_ws;

    a_histv<<<NSW + NSD + NST + 1, 1024, 0, stream>>>(
        wd_src, wd_dst, td_src, td_dst, Wwd, Wtd, Wout, ws);
    f_u<<<(NWORD + NTOPIC + 3) / 4, 256, 0, stream>>>(wemb, temb, ws);
    f_un<<<(NWN + NDOC + NTN + 255) / 256, 256, 0, stream>>>(word_ids, topic_ids, ws);
    d_edges_fin<<<NBLK_E, BDIM_E, 0, stream>>>(wd_src, wd_dst, td_src, td_dst,
                                               y_data, bwd, btd, Wout, bout, ws, out);
}